// Round 16
// baseline (1055.471 us; speedup 1.0000x reference)
//
#include <hip/hip_runtime.h>
#include <cstdint>
#include <cstddef>

#define SEQ 32768
#define DIM 1024
#define HID 128
#define KMAXV 103   // int(0.1*1024)+1

using f4 = __attribute__((ext_vector_type(4))) float;
using f2 = __attribute__((ext_vector_type(2))) float;

// ---------------------------------------------------------------------------
// Kernel A: per-block partial column sums of x (f64, deterministic order).
// ---------------------------------------------------------------------------
__global__ __launch_bounds__(256) void pool_partial(const float* __restrict__ x,
                                                    double* __restrict__ part) {
    const int b = blockIdx.x;
    const int t = threadIdx.x;
    const int r0 = b * 128;
    double s0 = 0.0, s1 = 0.0, s2 = 0.0, s3 = 0.0;
    for (int r = 0; r < 128; ++r) {
        const float* row = x + (size_t)(r0 + r) * DIM;
        s0 += (double)row[t];
        s1 += (double)row[t + 256];
        s2 += (double)row[t + 512];
        s3 += (double)row[t + 768];
    }
    double* p = part + (size_t)b * DIM;
    p[t] = s0; p[t + 256] = s1; p[t + 512] = s2; p[t + 768] = s3;
}

// ---------------------------------------------------------------------------
// Kernel B: finish pooling, complexity net (exact erf GELU, sigmoid), k.
// ---------------------------------------------------------------------------
__global__ __launch_bounds__(1024) void tiny_net(const double* __restrict__ part,
                                                 const float* __restrict__ w1,
                                                 const float* __restrict__ b1,
                                                 const float* __restrict__ w2,
                                                 const float* __restrict__ b2,
                                                 float* __restrict__ out_scalars,
                                                 int* __restrict__ kout) {
    __shared__ double pooled[DIM];
    __shared__ double hidv[HID];
    const int t = threadIdx.x;

    double s = 0.0;
    for (int b = 0; b < 256; ++b) s += part[(size_t)b * DIM + t];
    pooled[t] = s / (double)SEQ;
    __syncthreads();

    if (t < HID) {
        double h = (double)b1[t];
        for (int d = 0; d < DIM; ++d) h += pooled[d] * (double)w1[d * HID + t];
        h = 0.5 * h * (1.0 + erf(h * 0.70710678118654752440));
        hidv[t] = h;
    }
    __syncthreads();

    if (t == 0) {
        double z = (double)b2[0];
        for (int j = 0; j < HID; ++j) z += hidv[j] * (double)w2[j];
        double c = 1.0 / (1.0 + exp(-z));
        double ar = 0.01 + 0.09 * c;
        int k = (int)(ar * (double)DIM);  // trunc
        if (k < 1) k = 1;
        if (k > KMAXV) k = KMAXV;
        out_scalars[0] = (float)c;
        out_scalars[1] = (float)ar;
        out_scalars[2] = (float)k;
        *kout = k;
    }
}

// ---------------------------------------------------------------------------
// GEMM with numpy/OpenBLAS f32 semantics — NUMERICS FROZEN: per element,
// sequential-k IEEE fma within panels {384,320,320}, panel sums added in
// order ((P1+P2)+P3). v_pk_fma_f32 = independent IEEE fma per half; each
// column chain keeps the exact per-element op order of rounds 2..15.
//
// R16: R11's best-measured per-wave shape (8 rows x 4 cols/lane; per 4-k:
// 8 s_load_dwordx4 x + 4 dwordx4 w + 64 pk_fma) at 2x occupancy:
// 1024-thread blocks, BM=32 rows, 16 waves = 4 row-groups x 4 col-waves;
// 2 blocks/CU = 32 waves (cap) for all kernels. Mechanism under test: the
// residual ~23% VALU idle at R11's 43% occupancy is per-step SMEM drain
// that only other resident waves can hide.
// ---------------------------------------------------------------------------
#define BM 32
#define CBLOCK 1024

// one 4-k FMA step for 8 rows x 4 cols (R11-verbatim numerics)
__device__ __forceinline__ void fma_step4(const f4 xq[8],
                                          f4 w0, f4 w1, f4 w2, f4 w3,
                                          f2 acc[8][2]) {
    const f2 w0lo = __builtin_shufflevector(w0, w0, 0, 1);
    const f2 w0hi = __builtin_shufflevector(w0, w0, 2, 3);
    const f2 w1lo = __builtin_shufflevector(w1, w1, 0, 1);
    const f2 w1hi = __builtin_shufflevector(w1, w1, 2, 3);
    const f2 w2lo = __builtin_shufflevector(w2, w2, 0, 1);
    const f2 w2hi = __builtin_shufflevector(w2, w2, 2, 3);
    const f2 w3lo = __builtin_shufflevector(w3, w3, 0, 1);
    const f2 w3hi = __builtin_shufflevector(w3, w3, 2, 3);
#pragma unroll
    for (int m = 0; m < 8; ++m) {
        const f2 xab = __builtin_shufflevector(xq[m], xq[m], 0, 1);
        const f2 xcd = __builtin_shufflevector(xq[m], xq[m], 2, 3);
        asm("v_pk_fma_f32 %0, %1, %2, %0 op_sel:[0,0,0] op_sel_hi:[0,1,1]"
            : "+v"(acc[m][0]) : "s"(xab), "v"(w0lo));   // k+0
        asm("v_pk_fma_f32 %0, %1, %2, %0 op_sel:[0,0,0] op_sel_hi:[0,1,1]"
            : "+v"(acc[m][1]) : "s"(xab), "v"(w0hi));
        asm("v_pk_fma_f32 %0, %1, %2, %0 op_sel:[1,0,0] op_sel_hi:[1,1,1]"
            : "+v"(acc[m][0]) : "s"(xab), "v"(w1lo));   // k+1
        asm("v_pk_fma_f32 %0, %1, %2, %0 op_sel:[1,0,0] op_sel_hi:[1,1,1]"
            : "+v"(acc[m][1]) : "s"(xab), "v"(w1hi));
        asm("v_pk_fma_f32 %0, %1, %2, %0 op_sel:[0,0,0] op_sel_hi:[0,1,1]"
            : "+v"(acc[m][0]) : "s"(xcd), "v"(w2lo));   // k+2
        asm("v_pk_fma_f32 %0, %1, %2, %0 op_sel:[0,0,0] op_sel_hi:[0,1,1]"
            : "+v"(acc[m][1]) : "s"(xcd), "v"(w2hi));
        asm("v_pk_fma_f32 %0, %1, %2, %0 op_sel:[1,0,0] op_sel_hi:[1,1,1]"
            : "+v"(acc[m][0]) : "s"(xcd), "v"(w3lo));   // k+3
        asm("v_pk_fma_f32 %0, %1, %2, %0 op_sel:[1,0,0] op_sel_hi:[1,1,1]"
            : "+v"(acc[m][1]) : "s"(xcd), "v"(w3hi));
    }
}

template<int K0, int K1>
__device__ __forceinline__ void panel_acc4(const float* __restrict__ xbase,
                                           const float* __restrict__ wbase,
                                           f2 acc[8][2]) {
#pragma unroll
    for (int m = 0; m < 8; ++m) {
        acc[m][0][0] = 0.0f; acc[m][0][1] = 0.0f;
        acc[m][1][0] = 0.0f; acc[m][1][1] = 0.0f;
    }

    for (int kk0 = K0; kk0 < K1; kk0 += 4) {
        const f4 w0 = *(const f4*)(wbase + (size_t)(kk0 + 0) * DIM);
        const f4 w1 = *(const f4*)(wbase + (size_t)(kk0 + 1) * DIM);
        const f4 w2 = *(const f4*)(wbase + (size_t)(kk0 + 2) * DIM);
        const f4 w3 = *(const f4*)(wbase + (size_t)(kk0 + 3) * DIM);
        f4 xq[8];
#pragma unroll
        for (int m = 0; m < 8; ++m)
            xq[m] = *(const f4*)(xbase + m * DIM + kk0);   // s_load_dwordx4
        fma_step4(xq, w0, w1, w2, w3, acc);
    }
}

__device__ __forceinline__ f4 acc_to_f4(const f2 a[2]) {
    return __builtin_shufflevector(a[0], a[1], 0, 1, 2, 3);
}

__global__ __launch_bounds__(CBLOCK) void panel1_kernel(const float* __restrict__ x,
                                                        const float* __restrict__ wg,
                                                        float* __restrict__ out) {
    const int t = threadIdx.x;
    const int lane = t & 63;
    const int wid = t >> 6;                                   // 0..15
    const int cw = wid & 3;                                   // col-wave
    const int rg = __builtin_amdgcn_readfirstlane(wid >> 2);  // row-group 0..3
    const int c4 = (cw << 8) + (lane << 2);
    const int row0 = blockIdx.x * BM + rg * 8;

    f2 acc[8][2];
    panel_acc4<0, 384>(x + (size_t)row0 * DIM, wg + c4, acc);

#pragma unroll
    for (int m = 0; m < 8; ++m)
        *(f4*)(out + (size_t)(row0 + m) * DIM + c4) = acc_to_f4(acc[m]);
}

__global__ __launch_bounds__(CBLOCK) void panel2_kernel(const float* __restrict__ x,
                                                        const float* __restrict__ wg,
                                                        float* __restrict__ out) {
    const int t = threadIdx.x;
    const int lane = t & 63;
    const int wid = t >> 6;
    const int cw = wid & 3;
    const int rg = __builtin_amdgcn_readfirstlane(wid >> 2);
    const int c4 = (cw << 8) + (lane << 2);
    const int row0 = blockIdx.x * BM + rg * 8;

    f2 acc[8][2];
    panel_acc4<384, 704>(x + (size_t)row0 * DIM, wg + c4, acc);

#pragma unroll
    for (int m = 0; m < 8; ++m) {
        float* op = out + (size_t)(row0 + m) * DIM + c4;
        f4 d = *(const f4*)op;
        const f4 p = acc_to_f4(acc[m]);
#pragma unroll
        for (int j = 0; j < 4; ++j) d[j] = d[j] + p[j];   // fl(P1+P2)
        *(f4*)op = d;
    }
}

__global__ __launch_bounds__(CBLOCK) void panel3_kernel(const float* __restrict__ x,
                                                        const float* __restrict__ wg,
                                                        const float* __restrict__ bg,
                                                        const float* __restrict__ rm,
                                                        const float* __restrict__ rv,
                                                        const int* __restrict__ kptr,
                                                        float* __restrict__ out) {
    __shared__ float selbuf[16][DIM];    // 64 KB, staged 16 rows per chunk

    const int t = threadIdx.x;
    const int lane = t & 63;
    const int wid = t >> 6;
    const int cw = wid & 3;
    const int rg = __builtin_amdgcn_readfirstlane(wid >> 2);
    const int c4 = (cw << 8) + (lane << 2);
    const int row0 = blockIdx.x * BM + rg * 8;

    f2 acc[8][2];
    panel_acc4<704, 1024>(x + (size_t)row0 * DIM, wg + c4, acc);

    f4 dot[8];
#pragma unroll
    for (int m = 0; m < 8; ++m) {
        const f4 d = *(const f4*)(out + (size_t)(row0 + m) * DIM + c4);
        const f4 p = acc_to_f4(acc[m]);
#pragma unroll
        for (int j = 0; j < 4; ++j) dot[m][j] = d[j] + p[j];  // fl((P1+P2)+P3)
    }

    // f32 epilogue, op-for-op as numpy
    const f4 vbg = *(const f4*)(bg + c4);
    const f4 vrm = *(const f4*)(rm + c4);
    const f4 vrv = *(const f4*)(rv + c4);
    f4 vden;
#pragma unroll
    for (int j = 0; j < 4; ++j) vden[j] = sqrtf(vrv[j]) + 1e-6f;

    f4 imp[8];
#pragma unroll
    for (int m = 0; m < 8; ++m)
#pragma unroll
        for (int j = 0; j < 4; ++j)
            imp[m][j] = (fabsf(dot[m][j] + vbg[j]) - vrm[j]) / vden[j];

    int kval = *kptr;
    if (kval < 1) kval = 1;
    if (kval > DIM) kval = DIM;

    // two chunks of 16 rows; 16 waves <-> 16 rows per chunk
    for (int ch = 0; ch < 2; ++ch) {
        __syncthreads();
        if ((rg >> 1) == ch) {
#pragma unroll
            for (int m = 0; m < 8; ++m)
                *(f4*)(&selbuf[(rg & 1) * 8 + m][c4]) = imp[m];
        }
        __syncthreads();

        const size_t srow = (size_t)(blockIdx.x * BM + ch * 16 + wid);

        // monotonic u32 keys for descending f32 order
        unsigned keys[16];
#pragma unroll
        for (int j = 0; j < 4; ++j) {
            const f4 v = *(const f4*)(&selbuf[wid][4 * lane + 256 * j]);
#pragma unroll
            for (int i = 0; i < 4; ++i) {
                const unsigned u = __float_as_uint(v[i]);
                keys[j * 4 + i] = (u & 0x80000000u) ? ~u : (u | 0x80000000u);
            }
        }

        // bitwise search for the kth-largest key: largest T with count(>=T) >= k
        unsigned pref = 0u;
        for (int b = 31; b >= 0; --b) {
            const unsigned tt = pref | (1u << b);
            int cnt = 0;
#pragma unroll
            for (int j = 0; j < 16; ++j) cnt += (keys[j] >= tt) ? 1 : 0;
#pragma unroll
            for (int off = 32; off >= 1; off >>= 1) cnt += __shfl_xor(cnt, off, 64);
            if (cnt >= kval) pref = tt;
        }

        // mask = importance >= kth (tie-inclusive); coalesced float4 out
        const float* xr = x + srow * DIM;
        float* orow = out + srow * DIM;
#pragma unroll
        for (int j = 0; j < 4; ++j) {
            const f4 xv = *(const f4*)(xr + 4 * lane + 256 * j);
            f4 o;
#pragma unroll
            for (int i = 0; i < 4; ++i) o[i] = (keys[j * 4 + i] >= pref) ? xv[i] : 0.0f;
            *(f4*)(orow + 4 * lane + 256 * j) = o;
        }
    }
}

// ---------------------------------------------------------------------------
extern "C" void kernel_launch(void* const* d_in, const int* in_sizes, int n_in,
                              void* d_out, int out_size, void* d_ws, size_t ws_size,
                              hipStream_t stream) {
    const float* x  = (const float*)d_in[0];
    const float* w1 = (const float*)d_in[1];
    const float* b1 = (const float*)d_in[2];
    const float* w2 = (const float*)d_in[3];
    const float* b2 = (const float*)d_in[4];
    const float* wg = (const float*)d_in[5];
    const float* bg = (const float*)d_in[6];
    const float* rm = (const float*)d_in[7];
    const float* rv = (const float*)d_in[8];
    float* out = (float*)d_out;

    double* part = (double*)d_ws;                                  // 256*1024 f64 = 2 MB
    int* kptr = (int*)((char*)d_ws + (size_t)256 * DIM * sizeof(double));

    pool_partial<<<256, 256, 0, stream>>>(x, part);
    tiny_net<<<1, 1024, 0, stream>>>(part, w1, b1, w2, b2,
                                     out + (size_t)SEQ * DIM, kptr);
    panel1_kernel<<<SEQ / BM, CBLOCK, 0, stream>>>(x, wg, out);
    panel2_kernel<<<SEQ / BM, CBLOCK, 0, stream>>>(x, wg, out);
    panel3_kernel<<<SEQ / BM, CBLOCK, 0, stream>>>(x, wg, bg, rm, rv, kptr, out);
}

// Round 17
// 988.350 us; speedup vs baseline: 1.0679x; 1.0679x over previous
//
#include <hip/hip_runtime.h>
#include <cstdint>
#include <cstddef>

#define SEQ 32768
#define DIM 1024
#define HID 128
#define KMAXV 103   // int(0.1*1024)+1

using f4 = __attribute__((ext_vector_type(4))) float;
using f2 = __attribute__((ext_vector_type(2))) float;

// ---------------------------------------------------------------------------
// Kernel A: per-block partial column sums of x (f64, deterministic order).
// ---------------------------------------------------------------------------
__global__ __launch_bounds__(256) void pool_partial(const float* __restrict__ x,
                                                    double* __restrict__ part) {
    const int b = blockIdx.x;
    const int t = threadIdx.x;
    const int r0 = b * 128;
    double s0 = 0.0, s1 = 0.0, s2 = 0.0, s3 = 0.0;
    for (int r = 0; r < 128; ++r) {
        const float* row = x + (size_t)(r0 + r) * DIM;
        s0 += (double)row[t];
        s1 += (double)row[t + 256];
        s2 += (double)row[t + 512];
        s3 += (double)row[t + 768];
    }
    double* p = part + (size_t)b * DIM;
    p[t] = s0; p[t + 256] = s1; p[t + 512] = s2; p[t + 768] = s3;
}

// ---------------------------------------------------------------------------
// Kernel B: finish pooling, complexity net (exact erf GELU, sigmoid), k.
// ---------------------------------------------------------------------------
__global__ __launch_bounds__(1024) void tiny_net(const double* __restrict__ part,
                                                 const float* __restrict__ w1,
                                                 const float* __restrict__ b1,
                                                 const float* __restrict__ w2,
                                                 const float* __restrict__ b2,
                                                 float* __restrict__ out_scalars,
                                                 int* __restrict__ kout) {
    __shared__ double pooled[DIM];
    __shared__ double hidv[HID];
    const int t = threadIdx.x;

    double s = 0.0;
    for (int b = 0; b < 256; ++b) s += part[(size_t)b * DIM + t];
    pooled[t] = s / (double)SEQ;
    __syncthreads();

    if (t < HID) {
        double h = (double)b1[t];
        for (int d = 0; d < DIM; ++d) h += pooled[d] * (double)w1[d * HID + t];
        h = 0.5 * h * (1.0 + erf(h * 0.70710678118654752440));
        hidv[t] = h;
    }
    __syncthreads();

    if (t == 0) {
        double z = (double)b2[0];
        for (int j = 0; j < HID; ++j) z += hidv[j] * (double)w2[j];
        double c = 1.0 / (1.0 + exp(-z));
        double ar = 0.01 + 0.09 * c;
        int k = (int)(ar * (double)DIM);  // trunc
        if (k < 1) k = 1;
        if (k > KMAXV) k = KMAXV;
        out_scalars[0] = (float)c;
        out_scalars[1] = (float)ar;
        out_scalars[2] = (float)k;
        *kout = k;
    }
}

// ---------------------------------------------------------------------------
// GEMM with numpy/OpenBLAS f32 semantics — NUMERICS FROZEN: per element,
// sequential-k IEEE fma within panels {384,320,320}, panel sums added in
// order ((P1+P2)+P3). v_pk_fma_f32 = independent IEEE fma per half; each
// column chain keeps the exact per-element op order of rounds 2..16.
//
// R17 = best-of-measured composite:
//   p1/p2: R10 shape (2 cols/thread, 16 rows; minimal wq L2 traffic) —
//          measured fastest for the partial-only panels (~540 us combined).
//   p3:    R11 shape (4 cols/thread, 2 row-groups; 8 s_load_dwordx4 per
//          4-k step) — measured fastest where selection+epilogue amortize
//          the extra wq traffic (370 vs 405 us).
// Partial values in `out` are bit-identical under either thread mapping, so
// mixing mappings across kernels cannot change results.
// ---------------------------------------------------------------------------
#define BM 16
#define CBLOCK 512

// ------------------------- R10-shape pieces (p1/p2) ------------------------
__device__ __forceinline__ void fma_step2(const float* __restrict__ xp,
                                          f2 w0, f2 w1, f2 w2, f2 w3,
                                          f2 acc[16]) {
#pragma unroll
    for (int m = 0; m < 16; ++m) {
        const f2 xab = *(const f2*)(xp + m * DIM);      // uniform -> s_load_dwordx2
        const f2 xcd = *(const f2*)(xp + m * DIM + 2);
        asm("v_pk_fma_f32 %0, %1, %2, %0 op_sel:[0,0,0] op_sel_hi:[0,1,1]"
            : "+v"(acc[m]) : "s"(xab), "v"(w0));        // k+0
        asm("v_pk_fma_f32 %0, %1, %2, %0 op_sel:[1,0,0] op_sel_hi:[1,1,1]"
            : "+v"(acc[m]) : "s"(xab), "v"(w1));        // k+1
        asm("v_pk_fma_f32 %0, %1, %2, %0 op_sel:[0,0,0] op_sel_hi:[0,1,1]"
            : "+v"(acc[m]) : "s"(xcd), "v"(w2));        // k+2
        asm("v_pk_fma_f32 %0, %1, %2, %0 op_sel:[1,0,0] op_sel_hi:[1,1,1]"
            : "+v"(acc[m]) : "s"(xcd), "v"(w3));        // k+3
    }
}

template<int K0, int K1>
__device__ __forceinline__ void panel_acc2(const float* __restrict__ xbase,
                                           const float* __restrict__ wbase,
                                           f2 acc[16]) {
#pragma unroll
    for (int m = 0; m < 16; ++m) { acc[m][0] = 0.0f; acc[m][1] = 0.0f; }

    f2 a0 = *(const f2*)(wbase + (size_t)(K0 + 0) * DIM);
    f2 a1 = *(const f2*)(wbase + (size_t)(K0 + 1) * DIM);
    f2 a2 = *(const f2*)(wbase + (size_t)(K0 + 2) * DIM);
    f2 a3 = *(const f2*)(wbase + (size_t)(K0 + 3) * DIM);

    for (int kk0 = K0; kk0 < K1; kk0 += 8) {
        const f2 b0 = *(const f2*)(wbase + (size_t)(kk0 + 4) * DIM);
        const f2 b1 = *(const f2*)(wbase + (size_t)(kk0 + 5) * DIM);
        const f2 b2v = *(const f2*)(wbase + (size_t)(kk0 + 6) * DIM);
        const f2 b3 = *(const f2*)(wbase + (size_t)(kk0 + 7) * DIM);

        fma_step2(xbase + kk0, a0, a1, a2, a3, acc);     // k = kk0..kk0+3

        const int kn = (kk0 + 8 < K1) ? kk0 + 8 : K0;    // tail: dummy reload
        const f2 c0 = *(const f2*)(wbase + (size_t)(kn + 0) * DIM);
        const f2 c1 = *(const f2*)(wbase + (size_t)(kn + 1) * DIM);
        const f2 c2v = *(const f2*)(wbase + (size_t)(kn + 2) * DIM);
        const f2 c3 = *(const f2*)(wbase + (size_t)(kn + 3) * DIM);

        fma_step2(xbase + kk0 + 4, b0, b1, b2v, b3, acc); // k = kk0+4..kk0+7

        a0 = c0; a1 = c1; a2 = c2v; a3 = c3;
    }
}

__global__ __launch_bounds__(CBLOCK) void panel1_kernel(const float* __restrict__ x,
                                                        const float* __restrict__ wg,
                                                        float* __restrict__ out) {
    const int t = threadIdx.x;
    const int c2 = t << 1;
    const int row0 = blockIdx.x * BM;

    f2 pacc[16];
    panel_acc2<0, 384>(x + (size_t)row0 * DIM, wg + c2, pacc);

#pragma unroll
    for (int m = 0; m < 16; ++m)
        *(f2*)(out + (size_t)(row0 + m) * DIM + c2) = pacc[m];
}

__global__ __launch_bounds__(CBLOCK) void panel2_kernel(const float* __restrict__ x,
                                                        const float* __restrict__ wg,
                                                        float* __restrict__ out) {
    const int t = threadIdx.x;
    const int c2 = t << 1;
    const int row0 = blockIdx.x * BM;

    f2 pacc[16];
    panel_acc2<384, 704>(x + (size_t)row0 * DIM, wg + c2, pacc);

#pragma unroll
    for (int m = 0; m < 16; ++m) {
        float* op = out + (size_t)(row0 + m) * DIM + c2;
        f2 d = *(const f2*)op;
        d[0] = d[0] + pacc[m][0];       // fl(P1+P2), plain f32 adds
        d[1] = d[1] + pacc[m][1];
        *(f2*)op = d;
    }
}

// ------------------------- R11-shape pieces (p3) ---------------------------
__device__ __forceinline__ void fma_step4(const f4 xq[8],
                                          f4 w0, f4 w1, f4 w2, f4 w3,
                                          f2 acc[8][2]) {
    const f2 w0lo = __builtin_shufflevector(w0, w0, 0, 1);
    const f2 w0hi = __builtin_shufflevector(w0, w0, 2, 3);
    const f2 w1lo = __builtin_shufflevector(w1, w1, 0, 1);
    const f2 w1hi = __builtin_shufflevector(w1, w1, 2, 3);
    const f2 w2lo = __builtin_shufflevector(w2, w2, 0, 1);
    const f2 w2hi = __builtin_shufflevector(w2, w2, 2, 3);
    const f2 w3lo = __builtin_shufflevector(w3, w3, 0, 1);
    const f2 w3hi = __builtin_shufflevector(w3, w3, 2, 3);
#pragma unroll
    for (int m = 0; m < 8; ++m) {
        const f2 xab = __builtin_shufflevector(xq[m], xq[m], 0, 1);
        const f2 xcd = __builtin_shufflevector(xq[m], xq[m], 2, 3);
        asm("v_pk_fma_f32 %0, %1, %2, %0 op_sel:[0,0,0] op_sel_hi:[0,1,1]"
            : "+v"(acc[m][0]) : "s"(xab), "v"(w0lo));   // k+0
        asm("v_pk_fma_f32 %0, %1, %2, %0 op_sel:[0,0,0] op_sel_hi:[0,1,1]"
            : "+v"(acc[m][1]) : "s"(xab), "v"(w0hi));
        asm("v_pk_fma_f32 %0, %1, %2, %0 op_sel:[1,0,0] op_sel_hi:[1,1,1]"
            : "+v"(acc[m][0]) : "s"(xab), "v"(w1lo));   // k+1
        asm("v_pk_fma_f32 %0, %1, %2, %0 op_sel:[1,0,0] op_sel_hi:[1,1,1]"
            : "+v"(acc[m][1]) : "s"(xab), "v"(w1hi));
        asm("v_pk_fma_f32 %0, %1, %2, %0 op_sel:[0,0,0] op_sel_hi:[0,1,1]"
            : "+v"(acc[m][0]) : "s"(xcd), "v"(w2lo));   // k+2
        asm("v_pk_fma_f32 %0, %1, %2, %0 op_sel:[0,0,0] op_sel_hi:[0,1,1]"
            : "+v"(acc[m][1]) : "s"(xcd), "v"(w2hi));
        asm("v_pk_fma_f32 %0, %1, %2, %0 op_sel:[1,0,0] op_sel_hi:[1,1,1]"
            : "+v"(acc[m][0]) : "s"(xcd), "v"(w3lo));   // k+3
        asm("v_pk_fma_f32 %0, %1, %2, %0 op_sel:[1,0,0] op_sel_hi:[1,1,1]"
            : "+v"(acc[m][1]) : "s"(xcd), "v"(w3hi));
    }
}

template<int K0, int K1>
__device__ __forceinline__ void panel_acc4(const float* __restrict__ xbase,
                                           const float* __restrict__ wbase,
                                           f2 acc[8][2]) {
#pragma unroll
    for (int m = 0; m < 8; ++m) {
        acc[m][0][0] = 0.0f; acc[m][0][1] = 0.0f;
        acc[m][1][0] = 0.0f; acc[m][1][1] = 0.0f;
    }

    f4 wA0 = *(const f4*)(wbase + (size_t)(K0 + 0) * DIM);
    f4 wA1 = *(const f4*)(wbase + (size_t)(K0 + 1) * DIM);
    f4 wA2 = *(const f4*)(wbase + (size_t)(K0 + 2) * DIM);
    f4 wA3 = *(const f4*)(wbase + (size_t)(K0 + 3) * DIM);

    for (int kk0 = K0; kk0 < K1; kk0 += 8) {
        const f4 wB0 = *(const f4*)(wbase + (size_t)(kk0 + 4) * DIM);
        const f4 wB1 = *(const f4*)(wbase + (size_t)(kk0 + 5) * DIM);
        const f4 wB2 = *(const f4*)(wbase + (size_t)(kk0 + 6) * DIM);
        const f4 wB3 = *(const f4*)(wbase + (size_t)(kk0 + 7) * DIM);

        f4 xq[8];
#pragma unroll
        for (int m = 0; m < 8; ++m)
            xq[m] = *(const f4*)(xbase + m * DIM + kk0);       // s_load_dwordx4
        fma_step4(xq, wA0, wA1, wA2, wA3, acc);                // k = kk0..kk0+3

        const int kn = (kk0 + 8 < K1) ? kk0 + 8 : K0;          // tail: dummy reload
        wA0 = *(const f4*)(wbase + (size_t)(kn + 0) * DIM);
        wA1 = *(const f4*)(wbase + (size_t)(kn + 1) * DIM);
        wA2 = *(const f4*)(wbase + (size_t)(kn + 2) * DIM);
        wA3 = *(const f4*)(wbase + (size_t)(kn + 3) * DIM);

#pragma unroll
        for (int m = 0; m < 8; ++m)
            xq[m] = *(const f4*)(xbase + m * DIM + kk0 + 4);
        fma_step4(xq, wB0, wB1, wB2, wB3, acc);                // k = kk0+4..kk0+7
    }
}

__device__ __forceinline__ f4 acc_to_f4(const f2 a[2]) {
    return __builtin_shufflevector(a[0], a[1], 0, 1, 2, 3);
}

__global__ __launch_bounds__(CBLOCK) void panel3_kernel(const float* __restrict__ x,
                                                        const float* __restrict__ wg,
                                                        const float* __restrict__ bg,
                                                        const float* __restrict__ rm,
                                                        const float* __restrict__ rv,
                                                        const int* __restrict__ kptr,
                                                        float* __restrict__ out) {
    __shared__ float lbuf[8 * DIM];

    const int t = threadIdx.x;
    const int c4 = (t & 255) << 2;
    const int rg = __builtin_amdgcn_readfirstlane(t >> 8);
    const int row0 = blockIdx.x * BM + rg * 8;

    f2 acc[8][2];
    panel_acc4<704, 1024>(x + (size_t)row0 * DIM, wg + c4, acc);

    f4 dot[8];
#pragma unroll
    for (int m = 0; m < 8; ++m) {
        const f4 d = *(const f4*)(out + (size_t)(row0 + m) * DIM + c4);
        const f4 p = acc_to_f4(acc[m]);
#pragma unroll
        for (int j = 0; j < 4; ++j) dot[m][j] = d[j] + p[j];  // fl((P1+P2)+P3)
    }

    // f32 epilogue, op-for-op as numpy
    const f4 vbg = *(const f4*)(bg + c4);
    const f4 vrm = *(const f4*)(rm + c4);
    const f4 vrv = *(const f4*)(rv + c4);
    f4 vden;
#pragma unroll
    for (int j = 0; j < 4; ++j) vden[j] = sqrtf(vrv[j]) + 1e-6f;

    f4 imp[8];
#pragma unroll
    for (int m = 0; m < 8; ++m)
#pragma unroll
        for (int j = 0; j < 4; ++j)
            imp[m][j] = (fabsf(dot[m][j] + vbg[j]) - vrm[j]) / vden[j];

    int kval = *kptr;
    if (kval < 1) kval = 1;
    if (kval > DIM) kval = DIM;

    float (*selbuf)[DIM] = (float (*)[DIM])lbuf;

    // two chunks of 8 rows; one wave per row does exact kth-largest selection
    for (int ch = 0; ch < 2; ++ch) {
        __syncthreads();
        if (rg == ch) {
#pragma unroll
            for (int m = 0; m < 8; ++m)
                *(f4*)(&selbuf[m][c4]) = imp[m];
        }
        __syncthreads();

        const int w = t >> 6;    // wave id 0..7 -> row within chunk
        const int l = t & 63;    // lane
        const size_t srow = (size_t)(blockIdx.x * BM + ch * 8 + w);

        // monotonic u32 keys for descending f32 order
        unsigned keys[16];
#pragma unroll
        for (int j = 0; j < 4; ++j) {
            const f4 v = *(const f4*)(&selbuf[w][4 * l + 256 * j]);
#pragma unroll
            for (int i = 0; i < 4; ++i) {
                const unsigned u = __float_as_uint(v[i]);
                keys[j * 4 + i] = (u & 0x80000000u) ? ~u : (u | 0x80000000u);
            }
        }

        // bitwise search for the kth-largest key: largest T with count(>=T) >= k
        unsigned pref = 0u;
        for (int b = 31; b >= 0; --b) {
            const unsigned tt = pref | (1u << b);
            int cnt = 0;
#pragma unroll
            for (int j = 0; j < 16; ++j) cnt += (keys[j] >= tt) ? 1 : 0;
#pragma unroll
            for (int off = 32; off >= 1; off >>= 1) cnt += __shfl_xor(cnt, off, 64);
            if (cnt >= kval) pref = tt;
        }

        // mask = importance >= kth (tie-inclusive); coalesced float4 out
        const float* xr = x + srow * DIM;
        float* orow = out + srow * DIM;
#pragma unroll
        for (int j = 0; j < 4; ++j) {
            const f4 xv = *(const f4*)(xr + 4 * l + 256 * j);
            f4 o;
#pragma unroll
            for (int i = 0; i < 4; ++i) o[i] = (keys[j * 4 + i] >= pref) ? xv[i] : 0.0f;
            *(f4*)(orow + 4 * l + 256 * j) = o;
        }
    }
}

// ---------------------------------------------------------------------------
extern "C" void kernel_launch(void* const* d_in, const int* in_sizes, int n_in,
                              void* d_out, int out_size, void* d_ws, size_t ws_size,
                              hipStream_t stream) {
    const float* x  = (const float*)d_in[0];
    const float* w1 = (const float*)d_in[1];
    const float* b1 = (const float*)d_in[2];
    const float* w2 = (const float*)d_in[3];
    const float* b2 = (const float*)d_in[4];
    const float* wg = (const float*)d_in[5];
    const float* bg = (const float*)d_in[6];
    const float* rm = (const float*)d_in[7];
    const float* rv = (const float*)d_in[8];
    float* out = (float*)d_out;

    double* part = (double*)d_ws;                                  // 256*1024 f64 = 2 MB
    int* kptr = (int*)((char*)d_ws + (size_t)256 * DIM * sizeof(double));

    pool_partial<<<256, 256, 0, stream>>>(x, part);
    tiny_net<<<1, 1024, 0, stream>>>(part, w1, b1, w2, b2,
                                     out + (size_t)SEQ * DIM, kptr);
    panel1_kernel<<<SEQ / BM, CBLOCK, 0, stream>>>(x, wg, out);
    panel2_kernel<<<SEQ / BM, CBLOCK, 0, stream>>>(x, wg, out);
    panel3_kernel<<<SEQ / BM, CBLOCK, 0, stream>>>(x, wg, bg, rm, rv, kptr, out);
}